// Round 1
// baseline (770.461 us; speedup 1.0000x reference)
//
#include <hip/hip_runtime.h>

#define BB 64
#define CC 1024
#define QQ 128
#define HH 512

// workspace layout (floats):
//   E      : BB*CC*QQ   = 8388608   (exp(S), unmasked)
//   rowsum : BB*CC      = 65536     (sum_q exp(S)*qmask)
//   colsum : BB*QQ      = 8192      (sum_c exp(S)*cmask)
//   sub0   : BB*QQ      = 8192
//   tmp    : BB*QQ*HH   = 4194304
// total ~48.3 MB

// ---------------- K0: sub0[b,q] = dot(xq[b,q,:], W0); also zero colsum ----
__global__ __launch_bounds__(256) void k_sub0(const float* __restrict__ xq,
                                              const float* __restrict__ w0,
                                              float* __restrict__ sub0,
                                              float* __restrict__ colsum) {
    // zero colsum (8192 floats) with the first 32 blocks
    if (blockIdx.x < 32) colsum[blockIdx.x * 256 + threadIdx.x] = 0.0f;

    int wave = threadIdx.x >> 6;
    int lane = threadIdx.x & 63;
    int row  = blockIdx.x * 4 + wave;          // [0, BB*QQ)
    const float* p = xq + (size_t)row * HH + lane * 8;
    float4 a0 = *(const float4*)(p);
    float4 a1 = *(const float4*)(p + 4);
    float4 b0 = *(const float4*)(w0 + lane * 8);
    float4 b1 = *(const float4*)(w0 + lane * 8 + 4);
    float s = a0.x*b0.x + a0.y*b0.y + a0.z*b0.z + a0.w*b0.w
            + a1.x*b1.x + a1.y*b1.y + a1.z*b1.z + a1.w*b1.w;
    #pragma unroll
    for (int off = 32; off; off >>= 1) s += __shfl_xor(s, off);
    if (lane == 0) sub0[row] = s;
}

// ---------------- K1: S tile -> E=exp(S), rowsum, colsum, fused sub1 ------
__global__ __launch_bounds__(256) void k_scores(
    const float* __restrict__ xc, const float* __restrict__ xq,
    const float* __restrict__ w1, const float* __restrict__ w2,
    const float* __restrict__ cmask, const float* __restrict__ qmask,
    const float* __restrict__ bias, const float* __restrict__ sub0,
    float* __restrict__ E, float* __restrict__ rowsum,
    float* __restrict__ colsum) {
    int b  = blockIdx.y;
    int c0 = blockIdx.x * 64;
    int tid = threadIdx.x;
    int ty = tid >> 4, tx = tid & 15;   // ty: c-group (4 c's), tx: q-group (8 q's)

    __shared__ float sA[32][64];     // [k][c]  (xc tile, transposed)
    __shared__ float sB[32][128];    // [k][q]  (xq*w2 tile, transposed)
    __shared__ float sSub1[64];
    __shared__ float sPart[16][128];

    float acc[4][8];
    #pragma unroll
    for (int i = 0; i < 4; i++)
        #pragma unroll
        for (int j = 0; j < 8; j++) acc[i][j] = 0.0f;
    float s1 = 0.0f;

    for (int h0 = 0; h0 < HH; h0 += 32) {
        #pragma unroll
        for (int t = 0; t < 2; t++) {      // stage A: 64c x 32k
            int idx = tid + t * 256;       // [0,512)
            int c = idx >> 3, kf = (idx & 7) << 2;
            float4 v = *(const float4*)(xc + ((size_t)b*CC + c0 + c)*HH + h0 + kf);
            sA[kf+0][c] = v.x; sA[kf+1][c] = v.y; sA[kf+2][c] = v.z; sA[kf+3][c] = v.w;
        }
        #pragma unroll
        for (int t = 0; t < 4; t++) {      // stage B: 128q x 32k, *w2
            int idx = tid + t * 256;       // [0,1024)
            int q = idx >> 3, kf = (idx & 7) << 2;
            float4 v = *(const float4*)(xq + ((size_t)b*QQ + q)*HH + h0 + kf);
            float4 w = *(const float4*)(w2 + h0 + kf);
            sB[kf+0][q] = v.x*w.x; sB[kf+1][q] = v.y*w.y;
            sB[kf+2][q] = v.z*w.z; sB[kf+3][q] = v.w*w.w;
        }
        __syncthreads();
        if (tid < 64) {                    // fused sub1 partial (wave 0)
            #pragma unroll
            for (int k = 0; k < 32; k++) s1 += sA[k][tid] * w1[h0 + k];
        }
        #pragma unroll 4
        for (int kk = 0; kk < 32; kk++) {
            float av[4], bv[8];
            *(float4*)av     = *(const float4*)&sA[kk][ty*4];
            *(float4*)bv     = *(const float4*)&sB[kk][tx*8];
            *(float4*)(bv+4) = *(const float4*)&sB[kk][tx*8+4];
            #pragma unroll
            for (int i = 0; i < 4; i++)
                #pragma unroll
                for (int j = 0; j < 8; j++) acc[i][j] += av[i] * bv[j];
        }
        __syncthreads();
    }

    if (tid < 64) sSub1[tid] = s1;
    __syncthreads();

    float s0v[8], qmv[8];
    *(float4*)s0v     = *(const float4*)(sub0  + b*QQ + tx*8);
    *(float4*)(s0v+4) = *(const float4*)(sub0  + b*QQ + tx*8 + 4);
    *(float4*)qmv     = *(const float4*)(qmask + b*QQ + tx*8);
    *(float4*)(qmv+4) = *(const float4*)(qmask + b*QQ + tx*8 + 4);
    float bias0 = bias[0];
    float colp[8];
    #pragma unroll
    for (int j = 0; j < 8; j++) colp[j] = 0.0f;

    #pragma unroll
    for (int i = 0; i < 4; i++) {
        int c = c0 + ty*4 + i;
        float mcv = cmask[b*CC + c];
        float sb1 = sSub1[ty*4 + i];
        float ev[8];
        float rsum = 0.0f;
        #pragma unroll
        for (int j = 0; j < 8; j++) {
            float S = acc[i][j] + sb1 + s0v[j] + bias0;
            float e = __expf(S);           // no max-subtract: S bounded ~|15|
            ev[j] = e;
            rsum += e * qmv[j];
            colp[j] += e * mcv;
        }
        float* ep = E + ((size_t)b*CC + c)*QQ + tx*8;
        *(float4*)ep     = *(float4*)ev;
        *(float4*)(ep+4) = *(float4*)(ev+4);
        #pragma unroll
        for (int off = 1; off < 16; off <<= 1) rsum += __shfl_xor(rsum, off);
        if (tx == 0) rowsum[(size_t)b*CC + c] = rsum;
    }

    *(float4*)&sPart[ty][tx*8]   = *(float4*)colp;
    *(float4*)&sPart[ty][tx*8+4] = *(float4*)(colp+4);
    __syncthreads();
    if (tid < 128) {
        float s = 0.0f;
        #pragma unroll
        for (int r = 0; r < 16; r++) s += sPart[r][tid];
        atomicAdd(&colsum[b*QQ + tid], s);
    }
}

// ---------------- K2: tmp[b,q,h] = sum_c (E*mc/colsum)[c,q] * xc[c,h] -----
__global__ __launch_bounds__(256) void k_tmp(
    const float* __restrict__ E, const float* __restrict__ xc,
    const float* __restrict__ cmask, const float* __restrict__ colsum,
    float* __restrict__ tmp) {
    int b  = blockIdx.z;
    int q0 = blockIdx.y * 64;
    int h0 = blockIdx.x * 64;
    int tid = threadIdx.x;
    int ty = tid >> 4, tx = tid & 15;   // ty: q-group, tx: h-group
    __shared__ float sE[32][64];        // [c][q]
    __shared__ float sX[32][64];        // [c][h]
    float acc[4][4];
    #pragma unroll
    for (int i = 0; i < 4; i++)
        #pragma unroll
        for (int j = 0; j < 4; j++) acc[i][j] = 0.0f;

    for (int cc0 = 0; cc0 < CC; cc0 += 32) {
        #pragma unroll
        for (int t = 0; t < 2; t++) {
            int idx = tid + t * 256;    // [0,512)
            int cc = idx >> 4, qf = (idx & 15) << 2;
            float mcv = cmask[b*CC + cc0 + cc];
            float4 v = *(const float4*)(E + ((size_t)b*CC + cc0 + cc)*QQ + q0 + qf);
            v.x *= mcv; v.y *= mcv; v.z *= mcv; v.w *= mcv;
            *(float4*)&sE[cc][qf] = v;
        }
        #pragma unroll
        for (int t = 0; t < 2; t++) {
            int idx = tid + t * 256;
            int cc = idx >> 4, hf = (idx & 15) << 2;
            float4 v = *(const float4*)(xc + ((size_t)b*CC + cc0 + cc)*HH + h0 + hf);
            *(float4*)&sX[cc][hf] = v;
        }
        __syncthreads();
        #pragma unroll 8
        for (int kk = 0; kk < 32; kk++) {
            float av[4], bv[4];
            *(float4*)av = *(const float4*)&sE[kk][ty*4];
            *(float4*)bv = *(const float4*)&sX[kk][tx*4];
            #pragma unroll
            for (int i = 0; i < 4; i++)
                #pragma unroll
                for (int j = 0; j < 4; j++) acc[i][j] += av[i] * bv[j];
        }
        __syncthreads();
    }
    #pragma unroll
    for (int i = 0; i < 4; i++) {
        int q = q0 + ty*4 + i;
        float ic = 1.0f / colsum[b*QQ + q];
        float ov[4];
        #pragma unroll
        for (int j = 0; j < 4; j++) ov[j] = acc[i][j] * ic;
        *(float4*)(tmp + ((size_t)b*QQ + q)*HH + h0 + tx*4) = *(float4*)ov;
    }
}

// ---------------- K3: c2q = S_ @ xq ; q2c = S_ @ tmp  (shared A) ----------
__global__ __launch_bounds__(256) void k_out(
    const float* __restrict__ E, const float* __restrict__ xq,
    const float* __restrict__ tmp, const float* __restrict__ qmask,
    const float* __restrict__ rowsum, float* __restrict__ c2q,
    float* __restrict__ q2c) {
    int b  = blockIdx.z;
    int c0 = blockIdx.y * 64;
    int h0 = blockIdx.x * 64;
    int tid = threadIdx.x;
    int ty = tid >> 4, tx = tid & 15;   // ty: c-group, tx: h-group
    __shared__ float sAe[64][68];       // [c][k], pad 68 keeps f4 align + 2-way banks
    __shared__ float sBq[64][64];       // [k=q][h] xq*qm
    __shared__ float sBt[64][64];       // [k=q][h] tmp*qm
    float accA[4][4], accB[4][4];
    #pragma unroll
    for (int i = 0; i < 4; i++)
        #pragma unroll
        for (int j = 0; j < 4; j++) { accA[i][j] = 0.0f; accB[i][j] = 0.0f; }

    for (int k0 = 0; k0 < QQ; k0 += 64) {
        #pragma unroll
        for (int t = 0; t < 4; t++) {   // stage A: 64c x 64k
            int idx = tid + t * 256;    // [0,1024)
            int cl = idx >> 4, kf = (idx & 15) << 2;
            float4 v = *(const float4*)(E + ((size_t)b*CC + c0 + cl)*QQ + k0 + kf);
            *(float4*)&sAe[cl][kf] = v;
        }
        #pragma unroll
        for (int t = 0; t < 4; t++) {   // stage both B tiles: 64k x 64h
            int idx = tid + t * 256;
            int ql = idx >> 4, hf = (idx & 15) << 2;
            float qmv = qmask[b*QQ + k0 + ql];
            float4 v = *(const float4*)(xq  + ((size_t)b*QQ + k0 + ql)*HH + h0 + hf);
            v.x *= qmv; v.y *= qmv; v.z *= qmv; v.w *= qmv;
            *(float4*)&sBq[ql][hf] = v;
            float4 u = *(const float4*)(tmp + ((size_t)b*QQ + k0 + ql)*HH + h0 + hf);
            u.x *= qmv; u.y *= qmv; u.z *= qmv; u.w *= qmv;
            *(float4*)&sBt[ql][hf] = u;
        }
        __syncthreads();
        #pragma unroll 4
        for (int kk = 0; kk < 64; kk++) {
            float av[4], bq[4], bt[4];
            #pragma unroll
            for (int i = 0; i < 4; i++) av[i] = sAe[ty*4 + i][kk];
            *(float4*)bq = *(const float4*)&sBq[kk][tx*4];
            *(float4*)bt = *(const float4*)&sBt[kk][tx*4];
            #pragma unroll
            for (int i = 0; i < 4; i++)
                #pragma unroll
                for (int j = 0; j < 4; j++) {
                    accA[i][j] += av[i] * bq[j];
                    accB[i][j] += av[i] * bt[j];
                }
        }
        __syncthreads();
    }
    #pragma unroll
    for (int i = 0; i < 4; i++) {
        int c = c0 + ty*4 + i;
        float ir = 1.0f / rowsum[(size_t)b*CC + c];
        float oa[4], ob[4];
        #pragma unroll
        for (int j = 0; j < 4; j++) { oa[j] = accA[i][j]*ir; ob[j] = accB[i][j]*ir; }
        *(float4*)(c2q + ((size_t)b*CC + c)*HH + h0 + tx*4) = *(float4*)oa;
        *(float4*)(q2c + ((size_t)b*CC + c)*HH + h0 + tx*4) = *(float4*)ob;
    }
}

extern "C" void kernel_launch(void* const* d_in, const int* in_sizes, int n_in,
                              void* d_out, int out_size, void* d_ws, size_t ws_size,
                              hipStream_t stream) {
    const float* xc    = (const float*)d_in[0];
    const float* xq    = (const float*)d_in[1];
    const float* cmask = (const float*)d_in[2];
    const float* qmask = (const float*)d_in[3];
    const float* w0    = (const float*)d_in[4];
    const float* w1    = (const float*)d_in[5];
    const float* w2    = (const float*)d_in[6];
    const float* bias  = (const float*)d_in[7];

    float* out = (float*)d_out;
    float* c2q = out;
    float* q2c = out + (size_t)BB*CC*HH;

    float* E      = (float*)d_ws;                 // BB*CC*QQ
    float* rowsum = E + (size_t)BB*CC*QQ;         // BB*CC
    float* colsum = rowsum + (size_t)BB*CC;       // BB*QQ
    float* sub0   = colsum + (size_t)BB*QQ;       // BB*QQ
    float* tmp    = sub0 + (size_t)BB*QQ;         // BB*QQ*HH

    k_sub0  <<<dim3(BB*QQ/4),            256, 0, stream>>>(xq, w0, sub0, colsum);
    k_scores<<<dim3(CC/64, BB),          256, 0, stream>>>(xc, xq, w1, w2, cmask,
                                                           qmask, bias, sub0,
                                                           E, rowsum, colsum);
    k_tmp   <<<dim3(HH/64, QQ/64, BB),   256, 0, stream>>>(E, xc, cmask, colsum, tmp);
    k_out   <<<dim3(HH/64, CC/64, BB),   256, 0, stream>>>(E, xq, tmp, qmask,
                                                           rowsum, c2q, q2c);
}

// Round 2
// 477.143 us; speedup vs baseline: 1.6147x; 1.6147x over previous
//
#include <hip/hip_runtime.h>

#define BB 64
#define CC 1024
#define QQ 128
#define HH 512

typedef short bf16x8 __attribute__((ext_vector_type(8)));
typedef float f32x4 __attribute__((ext_vector_type(4)));

#define GLD16(g, l)                                                            \
    __builtin_amdgcn_global_load_lds(                                          \
        (const __attribute__((address_space(1))) unsigned int*)(g),            \
        (__attribute__((address_space(3))) unsigned int*)(l), 16, 0, 0)

__device__ __forceinline__ unsigned short f2bf(float f) {
    unsigned u = __float_as_uint(f);
    u += 0x7FFF + ((u >> 16) & 1);          // RNE
    return (unsigned short)(u >> 16);
}
__device__ __forceinline__ unsigned pk2(float lo, float hi) {
    return (unsigned)f2bf(lo) | ((unsigned)f2bf(hi) << 16);
}

// ---------------- K0: sub0[b,q] = dot(xq[b,q,:], W0); also zero colsum ----
__global__ __launch_bounds__(256) void k_sub0(const float* __restrict__ xq,
                                              const float* __restrict__ w0,
                                              float* __restrict__ sub0,
                                              float* __restrict__ colsum) {
    if (blockIdx.x < 32) colsum[blockIdx.x * 256 + threadIdx.x] = 0.0f;
    int wave = threadIdx.x >> 6;
    int lane = threadIdx.x & 63;
    int row  = blockIdx.x * 4 + wave;
    const float* p = xq + (size_t)row * HH + lane * 8;
    float4 a0 = *(const float4*)(p);
    float4 a1 = *(const float4*)(p + 4);
    float4 b0 = *(const float4*)(w0 + lane * 8);
    float4 b1 = *(const float4*)(w0 + lane * 8 + 4);
    float s = a0.x*b0.x + a0.y*b0.y + a0.z*b0.z + a0.w*b0.w
            + a1.x*b1.x + a1.y*b1.y + a1.z*b1.z + a1.w*b1.w;
    #pragma unroll
    for (int off = 32; off; off >>= 1) s += __shfl_xor(s, off);
    if (lane == 0) sub0[row] = s;
}

// ---------------- K_prep: xqw2b[q][h]=bf16(xq*w2); xqmT[h][q]=bf16(xq*qm) --
__global__ __launch_bounds__(256) void k_prep(const float* __restrict__ xq,
                                              const float* __restrict__ w2,
                                              const float* __restrict__ qmask,
                                              unsigned short* __restrict__ xqw2b,
                                              unsigned short* __restrict__ xqmT) {
    int b  = blockIdx.y;
    int ht = blockIdx.x * 128;
    int tid = threadIdx.x;
    __shared__ __align__(16) unsigned short sT[128][132];   // [q][h-local], pad

    {
        int q  = tid >> 1;
        int hh = (tid & 1) * 64;
        float qm = qmask[b * QQ + q];
        const float* xp = xq + ((size_t)b * QQ + q) * HH + ht + hh;
        unsigned short* wr = xqw2b + ((size_t)b * QQ + q) * HH + ht + hh;
        #pragma unroll
        for (int i = 0; i < 16; i++) {
            float4 v = *(const float4*)(xp + i * 4);
            float4 w = *(const float4*)(w2 + ht + hh + i * 4);
            uint2 pw; pw.x = pk2(v.x * w.x, v.y * w.y);
                      pw.y = pk2(v.z * w.z, v.w * w.w);
            *(uint2*)(wr + i * 4) = pw;
            uint2 pm; pm.x = pk2(v.x * qm, v.y * qm);
                      pm.y = pk2(v.z * qm, v.w * qm);
            *(uint2*)(&sT[q][hh + i * 4]) = pm;
        }
    }
    __syncthreads();
    {
        int h  = tid >> 1;
        int qh = (tid & 1) * 64;
        unsigned short* orow = xqmT + ((size_t)b * HH + ht + h) * QQ + qh;
        #pragma unroll
        for (int i = 0; i < 8; i++) {
            uint4 o;
            o.x = (unsigned)sT[qh + i*8 + 0][h] | ((unsigned)sT[qh + i*8 + 1][h] << 16);
            o.y = (unsigned)sT[qh + i*8 + 2][h] | ((unsigned)sT[qh + i*8 + 3][h] << 16);
            o.z = (unsigned)sT[qh + i*8 + 4][h] | ((unsigned)sT[qh + i*8 + 5][h] << 16);
            o.w = (unsigned)sT[qh + i*8 + 6][h] | ((unsigned)sT[qh + i*8 + 7][h] << 16);
            *(uint4*)(orow + i * 8) = o;
        }
    }
}

// ---------------- K1: S = xc · xqw2^T (MFMA) -> E=exp(S), rowsum, colsum ---
__global__ __launch_bounds__(256) void k_scores(
    const float* __restrict__ xc, const unsigned short* __restrict__ xqw2b,
    const float* __restrict__ w1, const float* __restrict__ cmask,
    const float* __restrict__ qmask, const float* __restrict__ bias,
    const float* __restrict__ sub0, unsigned short* __restrict__ Ebf,
    float* __restrict__ rowsum, float* __restrict__ colsum) {
    int b  = blockIdx.y;
    int c0 = blockIdx.x * 128;
    int tid  = threadIdx.x;
    int lane = tid & 63, wave = tid >> 6;
    int quad = lane >> 4, lcol = lane & 15;
    int wrow = (wave >> 1) * 64, wcol = (wave & 1) * 64;

    __shared__ __align__(16) unsigned short sA[128][32];  // [c][k] bf16
    __shared__ __align__(16) unsigned short sB[128][32];  // [q][k] bf16
    __shared__ float sW1[512];
    __shared__ float sSub1[128];
    __shared__ float sS0[128], sQm[128], sCm[128];
    __shared__ float sRowP[2][128], sColP[2][128];

    sW1[tid] = w1[tid]; sW1[tid + 256] = w1[tid + 256];
    if (tid < 128) {
        sS0[tid] = sub0[b * QQ + tid] + bias[0];
        sQm[tid] = qmask[b * QQ + tid];
        sCm[tid] = cmask[b * CC + c0 + tid];
    }

    f32x4 acc[4][4];
    #pragma unroll
    for (int i = 0; i < 4; i++)
        #pragma unroll
        for (int j = 0; j < 4; j++) acc[i][j] = (f32x4)0.0f;
    float s1 = 0.0f;

    int arow = tid >> 1, akh = (tid & 1) * 16;

    for (int k0 = 0; k0 < HH; k0 += 32) {
        __syncthreads();
        // --- stage A: xc fp32 -> bf16, row-natural; fused sub1 partial ---
        {
            const float* gp = xc + ((size_t)(b * CC + c0 + arow)) * HH + k0 + akh;
            float4 v0 = *(const float4*)(gp);
            float4 v1 = *(const float4*)(gp + 4);
            float4 v2 = *(const float4*)(gp + 8);
            float4 v3 = *(const float4*)(gp + 12);
            const float* wp = sW1 + k0 + akh;
            s1 += v0.x*wp[0] + v0.y*wp[1] + v0.z*wp[2] + v0.w*wp[3]
                + v1.x*wp[4] + v1.y*wp[5] + v1.z*wp[6] + v1.w*wp[7]
                + v2.x*wp[8] + v2.y*wp[9] + v2.z*wp[10] + v2.w*wp[11]
                + v3.x*wp[12] + v3.y*wp[13] + v3.z*wp[14] + v3.w*wp[15];
            uint4 p0, p1;
            p0.x = pk2(v0.x, v0.y); p0.y = pk2(v0.z, v0.w);
            p0.z = pk2(v1.x, v1.y); p0.w = pk2(v1.z, v1.w);
            p1.x = pk2(v2.x, v2.y); p1.y = pk2(v2.z, v2.w);
            p1.z = pk2(v3.x, v3.y); p1.w = pk2(v3.z, v3.w);
            *(uint4*)&sA[arow][akh]     = p0;
            *(uint4*)&sA[arow][akh + 8] = p1;
        }
        // --- stage B: xqw2b bf16 direct to LDS ---
        #pragma unroll
        for (int j = 0; j < 2; j++) {
            int chunk = wave * 2 + j;
            int row = chunk * 16 + (lane >> 2);
            GLD16(xqw2b + ((size_t)b * QQ + row) * HH + k0 + (lane & 3) * 8,
                  (unsigned short*)sB + chunk * 512);
        }
        __syncthreads();
        // --- MFMA ---
        bf16x8 af[4];
        #pragma unroll
        for (int mi = 0; mi < 4; mi++)
            af[mi] = *(const bf16x8*)&sA[wrow + mi * 16 + lcol][quad * 8];
        #pragma unroll
        for (int ni = 0; ni < 4; ni++) {
            bf16x8 bfr = *(const bf16x8*)&sB[wcol + ni * 16 + lcol][quad * 8];
            #pragma unroll
            for (int mi = 0; mi < 4; mi++)
                acc[mi][ni] = __builtin_amdgcn_mfma_f32_16x16x32_bf16(
                    af[mi], bfr, acc[mi][ni], 0, 0, 0);
        }
    }

    // sub1 finalize
    s1 += __shfl_xor(s1, 1);
    if ((tid & 1) == 0) sSub1[arow] = s1;
    __syncthreads();

    // epilogue: E = exp(S), rowsum/colsum partials
    float rsp[4][4];
    float csp[4] = {0.f, 0.f, 0.f, 0.f};
    #pragma unroll
    for (int mi = 0; mi < 4; mi++)
        #pragma unroll
        for (int r = 0; r < 4; r++) rsp[mi][r] = 0.f;

    #pragma unroll
    for (int mi = 0; mi < 4; mi++) {
        #pragma unroll
        for (int ni = 0; ni < 4; ni++) {
            int col = wcol + ni * 16 + lcol;
            float qm = sQm[col], s0 = sS0[col];
            #pragma unroll
            for (int r = 0; r < 4; r++) {
                int row = wrow + mi * 16 + quad * 4 + r;
                float e = __expf(acc[mi][ni][r] + sSub1[row] + s0);
                acc[mi][ni][r] = e;
                rsp[mi][r] += e * qm;
                csp[ni] += e * sCm[row];
            }
        }
    }
    #pragma unroll
    for (int mi = 0; mi < 4; mi++)
        #pragma unroll
        for (int r = 0; r < 4; r++) {
            float v = rsp[mi][r];
            v += __shfl_xor(v, 1); v += __shfl_xor(v, 2);
            v += __shfl_xor(v, 4); v += __shfl_xor(v, 8);
            if (lcol == 0) sRowP[wave & 1][wrow + mi * 16 + quad * 4 + r] = v;
        }
    #pragma unroll
    for (int ni = 0; ni < 4; ni++) {
        float v = csp[ni];
        v += __shfl_xor(v, 16); v += __shfl_xor(v, 32);
        if (quad == 0) sColP[wave >> 1][wcol + ni * 16 + lcol] = v;
    }
    // E store (bf16 scalar)
    #pragma unroll
    for (int mi = 0; mi < 4; mi++)
        #pragma unroll
        for (int ni = 0; ni < 4; ni++) {
            int col = wcol + ni * 16 + lcol;
            #pragma unroll
            for (int r = 0; r < 4; r++) {
                int row = wrow + mi * 16 + quad * 4 + r;
                Ebf[((size_t)(b * CC + c0 + row)) * QQ + col] = f2bf(acc[mi][ni][r]);
            }
        }
    __syncthreads();
    if (tid < 128) {
        rowsum[(size_t)b * CC + c0 + tid] = sRowP[0][tid] + sRowP[1][tid];
        atomicAdd(&colsum[b * QQ + tid], sColP[0][tid] + sColP[1][tid]);
    }
}

// ---------------- K2: tmpT[h][q] = qm[q]/colsum[q] * sum_c E[c][q]*mc*xc[c][h]
__global__ __launch_bounds__(256) void k_tmp(
    const unsigned short* __restrict__ Ebf, const float* __restrict__ xc,
    const float* __restrict__ cmask, const float* __restrict__ qmask,
    const float* __restrict__ colsum, unsigned short* __restrict__ tmpT) {
    int b  = blockIdx.y;
    int h0 = blockIdx.x * 64;
    int tid  = threadIdx.x;
    int lane = tid & 63, wave = tid >> 6;
    int quad = lane >> 4, lcol = lane & 15;
    int wrow = (wave >> 1) * 64;      // q
    int wcol = (wave & 1) * 32;       // h

    __shared__ __align__(16) unsigned int sAu[128 * 16];  // [q][c-chunk] swizzled
    __shared__ __align__(16) unsigned int sBu[64 * 16];   // [h][c-chunk] swizzled
    __shared__ float sInv[128];
    if (tid < 128) sInv[tid] = qmask[b * QQ + tid] / colsum[b * QQ + tid];

    f32x4 acc[4][2];
    #pragma unroll
    for (int i = 0; i < 4; i++) { acc[i][0] = (f32x4)0.f; acc[i][1] = (f32x4)0.f; }

    int tp = tid >> 4;     // c-pair 0..15
    int tq = tid & 15;     // q-8group / h-4group

    for (int c0 = 0; c0 < CC; c0 += 32) {
        __syncthreads();
        // --- stage A: E rows (bf16) -> [q][c] transposed, swizzled ---
        {
            const unsigned short* ep = Ebf + ((size_t)b * CC + c0 + 2 * tp) * QQ + tq * 8;
            union { uint4 v; unsigned short s[8]; } r0, r1;
            r0.v = *(const uint4*)ep;
            r1.v = *(const uint4*)(ep + QQ);
            #pragma unroll
            for (int j = 0; j < 8; j++) {
                int q = tq * 8 + j;
                unsigned pk = (unsigned)r0.s[j] | ((unsigned)r1.s[j] << 16);
                sAu[q * 16 + (((tp >> 2) ^ (q >> 3 & 3)) << 2) + (tp & 3)] = pk;
            }
        }
        // --- stage B: xc fp32 -> bf16*cmask, [h][c] transposed, swizzled ---
        {
            const float* xp = xc + ((size_t)b * CC + c0 + 2 * tp) * HH + h0 + tq * 4;
            float cm0 = cmask[b * CC + c0 + 2 * tp];
            float cm1 = cmask[b * CC + c0 + 2 * tp + 1];
            float4 f0 = *(const float4*)xp;
            float4 f1 = *(const float4*)(xp + HH);
            float a0[4] = {f0.x, f0.y, f0.z, f0.w};
            float a1[4] = {f1.x, f1.y, f1.z, f1.w};
            #pragma unroll
            for (int j = 0; j < 4; j++) {
                int h = tq * 4 + j;
                unsigned pk = pk2(a0[j] * cm0, a1[j] * cm1);
                sBu[h * 16 + (((tp >> 2) ^ (h >> 3 & 3)) << 2) + (tp & 3)] = pk;
            }
        }
        __syncthreads();
        // --- MFMA ---
        bf16x8 af[4];
        #pragma unroll
        for (int mi = 0; mi < 4; mi++) {
            int m = wrow + mi * 16 + lcol;
            af[mi] = *(const bf16x8*)(sAu + m * 16 + ((quad ^ (m >> 3 & 3)) << 2));
        }
        #pragma unroll
        for (int ni = 0; ni < 2; ni++) {
            int n = wcol + ni * 16 + lcol;
            bf16x8 bfr = *(const bf16x8*)(sBu + n * 16 + ((quad ^ (n >> 3 & 3)) << 2));
            #pragma unroll
            for (int mi = 0; mi < 4; mi++)
                acc[mi][ni] = __builtin_amdgcn_mfma_f32_16x16x32_bf16(
                    af[mi], bfr, acc[mi][ni], 0, 0, 0);
        }
    }
    // epilogue: scale by qm/colsum, write tmpT[h][q] packed b64
    #pragma unroll
    for (int mi = 0; mi < 4; mi++) {
        int qb = wrow + mi * 16 + quad * 4;
        #pragma unroll
        for (int ni = 0; ni < 2; ni++) {
            int h = wcol + ni * 16 + lcol;
            uint2 o;
            o.x = pk2(acc[mi][ni][0] * sInv[qb + 0], acc[mi][ni][1] * sInv[qb + 1]);
            o.y = pk2(acc[mi][ni][2] * sInv[qb + 2], acc[mi][ni][3] * sInv[qb + 3]);
            *(uint2*)(tmpT + ((size_t)b * HH + h0 + h) * QQ + qb) = o;
        }
    }
}

// ---------------- K3: c2q = (E/rowsum)·xqm ; q2c = (E/rowsum)·tmpT^T -------
__global__ __launch_bounds__(256) void k_out(
    const unsigned short* __restrict__ Ebf, const unsigned short* __restrict__ xqmT,
    const unsigned short* __restrict__ tmpT, const float* __restrict__ rowsum,
    float* __restrict__ c2q, float* __restrict__ q2c) {
    int b  = blockIdx.z;
    int c0 = blockIdx.y * 128;
    int h0 = blockIdx.x * 128;
    int tid  = threadIdx.x;
    int lane = tid & 63, wave = tid >> 6;
    int quad = lane >> 4, lcol = lane & 15;
    int wrow = (wave >> 1) * 64, wcol = (wave & 1) * 64;

    __shared__ __align__(16) unsigned short sA[128][32];   // E   [c][q-chunk]
    __shared__ __align__(16) unsigned short sB1[128][32];  // xqmT[h][q-chunk]
    __shared__ __align__(16) unsigned short sB2[128][32];  // tmpT[h][q-chunk]
    __shared__ float sInvR[128];
    if (tid < 128) sInvR[tid] = 1.0f / rowsum[(size_t)b * CC + c0 + tid];

    f32x4 acc1[4][4], acc2[4][4];
    #pragma unroll
    for (int i = 0; i < 4; i++)
        #pragma unroll
        for (int j = 0; j < 4; j++) { acc1[i][j] = (f32x4)0.f; acc2[i][j] = (f32x4)0.f; }

    for (int k0 = 0; k0 < QQ; k0 += 32) {
        __syncthreads();
        #pragma unroll
        for (int j = 0; j < 2; j++) {
            int chunk = wave * 2 + j;
            int row = chunk * 16 + (lane >> 2);
            int kb  = (lane & 3) * 8;
            GLD16(Ebf  + ((size_t)b * CC + c0 + row) * QQ + k0 + kb,
                  (unsigned short*)sA + chunk * 512);
            GLD16(xqmT + ((size_t)b * HH + h0 + row) * QQ + k0 + kb,
                  (unsigned short*)sB1 + chunk * 512);
            GLD16(tmpT + ((size_t)b * HH + h0 + row) * QQ + k0 + kb,
                  (unsigned short*)sB2 + chunk * 512);
        }
        __syncthreads();
        bf16x8 af[4];
        #pragma unroll
        for (int mi = 0; mi < 4; mi++)
            af[mi] = *(const bf16x8*)&sA[wrow + mi * 16 + lcol][quad * 8];
        #pragma unroll
        for (int ni = 0; ni < 4; ni++) {
            bf16x8 b1 = *(const bf16x8*)&sB1[wcol + ni * 16 + lcol][quad * 8];
            bf16x8 b2 = *(const bf16x8*)&sB2[wcol + ni * 16 + lcol][quad * 8];
            #pragma unroll
            for (int mi = 0; mi < 4; mi++) {
                acc1[mi][ni] = __builtin_amdgcn_mfma_f32_16x16x32_bf16(
                    af[mi], b1, acc1[mi][ni], 0, 0, 0);
                acc2[mi][ni] = __builtin_amdgcn_mfma_f32_16x16x32_bf16(
                    af[mi], b2, acc2[mi][ni], 0, 0, 0);
            }
        }
    }
    #pragma unroll
    for (int mi = 0; mi < 4; mi++) {
        int rb = wrow + mi * 16 + quad * 4;
        float ir0 = sInvR[rb], ir1 = sInvR[rb + 1], ir2 = sInvR[rb + 2], ir3 = sInvR[rb + 3];
        #pragma unroll
        for (int ni = 0; ni < 4; ni++) {
            int col = h0 + wcol + ni * 16 + lcol;
            size_t o0 = ((size_t)b * CC + c0 + rb) * HH + col;
            c2q[o0]          = acc1[mi][ni][0] * ir0;
            c2q[o0 + HH]     = acc1[mi][ni][1] * ir1;
            c2q[o0 + 2*HH]   = acc1[mi][ni][2] * ir2;
            c2q[o0 + 3*HH]   = acc1[mi][ni][3] * ir3;
            q2c[o0]          = acc2[mi][ni][0] * ir0;
            q2c[o0 + HH]     = acc2[mi][ni][1] * ir1;
            q2c[o0 + 2*HH]   = acc2[mi][ni][2] * ir2;
            q2c[o0 + 3*HH]   = acc2[mi][ni][3] * ir3;
        }
    }
}

extern "C" void kernel_launch(void* const* d_in, const int* in_sizes, int n_in,
                              void* d_out, int out_size, void* d_ws, size_t ws_size,
                              hipStream_t stream) {
    const float* xc    = (const float*)d_in[0];
    const float* xq    = (const float*)d_in[1];
    const float* cmask = (const float*)d_in[2];
    const float* qmask = (const float*)d_in[3];
    const float* w0    = (const float*)d_in[4];
    const float* w1    = (const float*)d_in[5];
    const float* w2    = (const float*)d_in[6];
    const float* bias  = (const float*)d_in[7];

    float* out = (float*)d_out;
    float* c2q = out;
    float* q2c = out + (size_t)BB * CC * HH;

    unsigned short* Ebf   = (unsigned short*)d_ws;            // BB*CC*QQ
    unsigned short* xqw2b = Ebf   + (size_t)BB * CC * QQ;     // BB*QQ*HH
    unsigned short* xqmT  = xqw2b + (size_t)BB * QQ * HH;     // BB*HH*QQ
    unsigned short* tmpT  = xqmT  + (size_t)BB * QQ * HH;     // BB*HH*QQ
    float* rowsum = (float*)(tmpT + (size_t)BB * QQ * HH);    // BB*CC
    float* colsum = rowsum + (size_t)BB * CC;                 // BB*QQ
    float* sub0   = colsum + (size_t)BB * QQ;                 // BB*QQ

    k_sub0  <<<dim3(BB * QQ / 4),      256, 0, stream>>>(xq, w0, sub0, colsum);
    k_prep  <<<dim3(HH / 128, BB),     256, 0, stream>>>(xq, w2, qmask, xqw2b, xqmT);
    k_scores<<<dim3(CC / 128, BB),     256, 0, stream>>>(xc, xqw2b, w1, cmask, qmask,
                                                         bias, sub0, Ebf, rowsum, colsum);
    k_tmp   <<<dim3(HH / 64, BB),      256, 0, stream>>>(Ebf, xc, cmask, qmask,
                                                         colsum, tmpT);
    k_out   <<<dim3(HH / 128, CC / 128, BB), 256, 0, stream>>>(Ebf, xqmT, tmpT,
                                                               rowsum, c2q, q2c);
}